// Round 11
// baseline (580.273 us; speedup 1.0000x reference)
//
#include <hip/hip_runtime.h>
#include <hip/hip_bf16.h>

typedef __bf16 bf16;
typedef __attribute__((ext_vector_type(8))) __bf16 bf16x8;
typedef __attribute__((ext_vector_type(4))) float f32x4;

constexpr int N_NODES   = 100000;
constexpr int N_PAD     = 100032;   // multiple of 64
constexpr int D         = 128;
constexpr int D_FF      = 256;
constexpr int N_CLASSES = 26;
constexpr int N_GRAPHS  = 512;
constexpr int NB1       = 256;                       // partition blocks (CSR build)
constexpr int NBUCK     = (N_NODES + 511) / 512;     // 196 dst-buckets of 512 nodes

__device__ inline float2 bf2f(unsigned u) {
    float lo = __uint_as_float(u << 16);
    float hi = __uint_as_float(u & 0xffff0000u);
    return make_float2(lo, hi);
}

// ---------------- CSR build: atomic-free bucket counting sort ----------------
// R23: 3 launches. p3/p45 recompute their own prefix slices from the 200KB
// L2-resident gcount.

// p1 histogram (blocks 0..255) + misc work (blocks 256..320) in ONE launch.
__global__ __launch_bounds__(1024) void p1misc_kernel(const int* __restrict__ edst,
                                                      int* __restrict__ gcount, int e,
                                                      const int* __restrict__ batch,
                                                      int* __restrict__ starts, int n,
                                                      const float* __restrict__ W0,
                                                      const float* __restrict__ W1,
                                                      const float* __restrict__ W2,
                                                      bf16* __restrict__ WT3,
                                                      float* __restrict__ gsum) {
    int t = threadIdx.x;
    if (blockIdx.x < NB1) {
        __shared__ int cnt[NBUCK];
        for (int q = t; q < NBUCK; q += 1024) cnt[q] = 0;
        __syncthreads();
        int chunk = (e + NB1 - 1) / NB1;
        int lo = blockIdx.x * chunk;
        int hi = min(e, lo + chunk);
        for (int i = lo + t; i < hi; i += 1024)
            atomicAdd(&cnt[edst[i] >> 9], 1);
        __syncthreads();
        for (int q = t; q < NBUCK; q += 1024)
            gcount[q * NB1 + blockIdx.x] = cnt[q];
    } else {
        int mb = blockIdx.x - NB1;                 // 0..64
        if (mb == 0) {
            if (t <= N_GRAPHS) {                   // starts[g] = lower_bound(batch,g)
                int lo = 0, hi = n;
                while (lo < hi) {
                    int mid = (lo + hi) >> 1;
                    if (batch[mid] < t) lo = mid + 1; else hi = mid;
                }
                starts[t] = lo;
            }
        } else if (mb <= 48) {
            int idx = (mb - 1) * 1024 + t;         // 0..49151 == 3*128*128
            int l = idx >> 14;
            int rem = idx & 16383;
            int nn = rem >> 7;
            int kk = rem & 127;
            const float* W = (l == 0) ? W0 : (l == 1) ? W1 : W2;
            WT3[idx] = (bf16)W[kk * D + nn];       // WT3[l][n][k] = W[k][n]
        } else {
            int idx = (mb - 49) * 1024 + t;        // 16384 float4 = 512*128 f32
            f32x4 z = {0.f, 0.f, 0.f, 0.f};
            *((f32x4*)gsum + idx) = z;
        }
    }
}

// R23 self-scanning scatter: block b derives its per-bucket cursors directly
// from gcount: cur[t] = bucketbase[t] + sum_{c<b} gcount[t][c].
__global__ __launch_bounds__(1024) void p3_scatter(const int* __restrict__ gcount,
                                                   const int* __restrict__ esrc,
                                                   const int* __restrict__ edst,
                                                   int* __restrict__ ebuf, int e) {
    __shared__ int cur[NBUCK];
    __shared__ int tot[NBUCK];
    int t = threadIdx.x;
    int b = blockIdx.x;
    if (t < NBUCK) {
        int sum = 0, part = 0;
        const int* row = gcount + t * NB1;
        for (int c = 0; c < NB1; ++c) {
            int v = row[c];
            sum += v;
            part += (c < b) ? v : 0;
        }
        tot[t] = sum;
        cur[t] = part;
    }
    __syncthreads();
    for (int off = 1; off < NBUCK; off <<= 1) {   // inclusive scan of tot
        int v = (t >= off && t < NBUCK) ? tot[t - off] : 0;
        __syncthreads();
        if (t < NBUCK) tot[t] += v;
        __syncthreads();
    }
    if (t < NBUCK) cur[t] += (t > 0) ? tot[t - 1] : 0;   // + exclusive bucketbase
    __syncthreads();
    int chunk = (e + NB1 - 1) / NB1;
    int lo = b * chunk;
    int hi = min(e, lo + chunk);
    for (int i = lo + t; i < hi; i += 1024) {
        int d = edst[i], s = esrc[i];
        int pos = atomicAdd(&cur[d >> 9], 1);   // LDS atomic
        ebuf[pos] = (s << 9) | (d & 511);
    }
}

// R23 self-scanning P45: block b reduces its own lo/hi from gcount, then runs
// the fused per-bucket degree count + LDS scan + CSR fill.
__global__ __launch_bounds__(1024) void p45_fill(const int* __restrict__ gcount,
                                                 const int* __restrict__ ebuf,
                                                 float* __restrict__ dinv,
                                                 int* __restrict__ rowptr,
                                                 int* __restrict__ csrc, int e, int n) {
    __shared__ int red[1024];
    __shared__ int cnt[512];
    __shared__ int ps[512];
    __shared__ int cur[512];
    int b = blockIdx.x, t = threadIdx.x;
    // --- prefix slices from gcount ---
    int s1 = 0;
    for (int idx = t; idx < b * NB1; idx += 1024) s1 += gcount[idx];
    red[t] = s1; __syncthreads();
#pragma unroll
    for (int off = 512; off > 0; off >>= 1) {
        if (t < off) red[t] += red[t + off];
        __syncthreads();
    }
    int lo = red[0];
    __syncthreads();
    red[t] = (t < NB1) ? gcount[b * NB1 + t] : 0; __syncthreads();
#pragma unroll
    for (int off = 512; off > 0; off >>= 1) {
        if (t < off) red[t] += red[t + off];
        __syncthreads();
    }
    int hi = lo + red[0];
    __syncthreads();
    // --- original p45 body ---
    if (t < 512) cnt[t] = 0;
    __syncthreads();
    for (int i = lo + t; i < hi; i += 1024)
        atomicAdd(&cnt[ebuf[i] & 511], 1);      // LDS atomic
    __syncthreads();
    int a = (t < 512) ? cnt[t] : 0;
    if (t < 512) ps[t] = a;
    __syncthreads();
    for (int off = 1; off < 512; off <<= 1) {
        int v = (t >= off && t < 512) ? ps[t - off] : 0;
        __syncthreads();
        if (t < 512) ps[t] += v;
        __syncthreads();
    }
    if (t < 512) {
        int g0 = lo + ps[t] - a;             // global CSR slot of node b*512+t
        int node = b * 512 + t;
        cur[t] = g0;
        if (node < n) {
            rowptr[node] = g0;
            dinv[node] = 1.0f / sqrtf((float)(a + 1));   // +1 self-loop
        }
    }
    if (b == 0 && t == 0) rowptr[n] = e;
    __syncthreads();
    for (int i = lo + t; i < hi; i += 1024) {
        int pe = ebuf[i];
        int pos = atomicAdd(&cur[pe & 511], 1);  // LDS atomic
        csrc[pos] = pe >> 9;
    }
}

// ---------------- dense compute ----------------

// Layer-1: C[row][:] = bf16( dinv[row] * ((f32)A @ W)[row][:] ) — gather table g1.
__global__ __launch_bounds__(256) void gemm_f32_kernel(const float* __restrict__ A,
                                                       const bf16* __restrict__ WT,
                                                       bf16* __restrict__ C,
                                                       const float* __restrict__ dinv, int n) {
    int wave = threadIdx.x >> 6;
    int lane = threadIdx.x & 63;
    int m16  = lane & 15;
    int quad = lane >> 4;
    int row0 = blockIdx.x * 64 + wave * 16;
    int arowi = row0 + m16;

    bf16x8 a[4];
    const float* arow = A + (size_t)arowi * D + quad * 8;
#pragma unroll
    for (int kt = 0; kt < 4; ++kt) {
        float4 f0 = make_float4(0.f, 0.f, 0.f, 0.f);
        float4 f1 = make_float4(0.f, 0.f, 0.f, 0.f);
        if (arowi < n) {
            f0 = *(const float4*)(arow + kt * 32);
            f1 = *(const float4*)(arow + kt * 32 + 4);
        }
        bf16x8 v = { (bf16)f0.x, (bf16)f0.y, (bf16)f0.z, (bf16)f0.w,
                     (bf16)f1.x, (bf16)f1.y, (bf16)f1.z, (bf16)f1.w };
        a[kt] = v;
    }

    float sc[4];
#pragma unroll
    for (int r = 0; r < 4; ++r) {
        int rr = row0 + quad * 4 + r;
        sc[r] = (rr < n) ? dinv[rr] : 0.f;
    }

#pragma unroll
    for (int nt = 0; nt < 8; ++nt) {
        f32x4 acc = {0.f, 0.f, 0.f, 0.f};
        const bf16* brow = WT + (nt * 16 + m16) * D + quad * 8;
#pragma unroll
        for (int kt = 0; kt < 4; ++kt) {
            bf16x8 b = *(const bf16x8*)(brow + kt * 32);
            acc = __builtin_amdgcn_mfma_f32_16x16x32_bf16(a[kt], b, acc, 0, 0, 0);
        }
#pragma unroll
        for (int r = 0; r < 4; ++r)
            C[(row0 + quad * 4 + r) * D + nt * 16 + m16] = (bf16)(sc[r] * acc[r]);
    }
}

// ---------------- aggregation core (16 lanes own one node) ----------------
// acc = g[v] + sum_e g[src]   (table g pre-scaled by dinv[src])
// R24: 8-deep gather pipeline (R15 measured 2->4 deep = +3.6%; this pushes to
// the next rung). 8 csrc broadcasts + 8 row gathers issued before accumulation.
__device__ inline void acc_u4(float acc[8], uint4 u) {
    float2 f0 = bf2f(u.x), f1 = bf2f(u.y), f2 = bf2f(u.z), f3 = bf2f(u.w);
    acc[0] += f0.x; acc[1] += f0.y; acc[2] += f1.x; acc[3] += f1.y;
    acc[4] += f2.x; acc[5] += f2.y; acc[6] += f3.x; acc[7] += f3.y;
}

__device__ inline void agg_node(const bf16* __restrict__ h, int v, int n, int c,
                                const int* __restrict__ rowptr,
                                const int* __restrict__ csrc,
                                const float* __restrict__ dinv,
                                float& dv, float acc[8]) {
    int s = 0, e = 0;
    dv = 0.f;
    if (v < n) { s = rowptr[v]; e = rowptr[v + 1]; dv = dinv[v]; }
#pragma unroll
    for (int d = 0; d < 8; ++d) acc[d] = 0.f;
    if (v < n) {
        uint4 u = *(const uint4*)(h + (size_t)v * D + c * 8);
        acc_u4(acc, u);
    }
    int j = s;
    for (; j + 7 < e; j += 8) {
        int s0 = csrc[j],     s1 = csrc[j + 1], s2 = csrc[j + 2], s3 = csrc[j + 3];
        int s4 = csrc[j + 4], s5 = csrc[j + 5], s6 = csrc[j + 6], s7 = csrc[j + 7];
        uint4 u0 = *(const uint4*)(h + (size_t)s0 * D + c * 8);
        uint4 u1 = *(const uint4*)(h + (size_t)s1 * D + c * 8);
        uint4 u2 = *(const uint4*)(h + (size_t)s2 * D + c * 8);
        uint4 u3 = *(const uint4*)(h + (size_t)s3 * D + c * 8);
        uint4 u4 = *(const uint4*)(h + (size_t)s4 * D + c * 8);
        uint4 u5 = *(const uint4*)(h + (size_t)s5 * D + c * 8);
        uint4 u6 = *(const uint4*)(h + (size_t)s6 * D + c * 8);
        uint4 u7 = *(const uint4*)(h + (size_t)s7 * D + c * 8);
        acc_u4(acc, u0); acc_u4(acc, u1); acc_u4(acc, u2); acc_u4(acc, u3);
        acc_u4(acc, u4); acc_u4(acc, u5); acc_u4(acc, u6); acc_u4(acc, u7);
    }
    for (; j + 3 < e; j += 4) {
        int s0 = csrc[j], s1 = csrc[j + 1], s2 = csrc[j + 2], s3 = csrc[j + 3];
        uint4 u0 = *(const uint4*)(h + (size_t)s0 * D + c * 8);
        uint4 u1 = *(const uint4*)(h + (size_t)s1 * D + c * 8);
        uint4 u2 = *(const uint4*)(h + (size_t)s2 * D + c * 8);
        uint4 u3 = *(const uint4*)(h + (size_t)s3 * D + c * 8);
        acc_u4(acc, u0); acc_u4(acc, u1); acc_u4(acc, u2); acc_u4(acc, u3);
    }
    for (; j < e; ++j) {
        int s0 = csrc[j];
        uint4 u0 = *(const uint4*)(h + (size_t)s0 * D + c * 8);
        acc_u4(acc, u0);
    }
}

// Fused: aggregate layer l (16 nodes/block), relu-tile in LDS, then the
// block's 4 waves multiply by W_{l+1} (MFMA) and write the NEXT gather table
// g' = dinv * (h_l @ W_{l+1}).
__global__ __launch_bounds__(256) void spmm_gemm_kernel(const bf16* __restrict__ h,
                                                        const int* __restrict__ rowptr,
                                                        const int* __restrict__ csrc,
                                                        const float* __restrict__ dinv,
                                                        const float* __restrict__ bias,
                                                        const bf16* __restrict__ WT,
                                                        bf16* __restrict__ C, int n) {
    __shared__ bf16 tile[16][136];          // +8 bf16 row pad (bank spread)
    int t = threadIdx.x;
    int grp = t >> 4;                        // node within block
    int c   = t & 15;                        // dim chunk
    int v   = blockIdx.x * 16 + grp;
    float dv, acc[8];
    agg_node(h, v, n, c, rowptr, csrc, dinv, dv, acc);
    {
        float4 bi0 = *(const float4*)(bias + c * 8);
        float4 bi1 = *(const float4*)(bias + c * 8 + 4);
        bf16x8 o;
        o[0] = (bf16)fmaxf(fmaf(dv, acc[0], bi0.x), 0.f);
        o[1] = (bf16)fmaxf(fmaf(dv, acc[1], bi0.y), 0.f);
        o[2] = (bf16)fmaxf(fmaf(dv, acc[2], bi0.z), 0.f);
        o[3] = (bf16)fmaxf(fmaf(dv, acc[3], bi0.w), 0.f);
        o[4] = (bf16)fmaxf(fmaf(dv, acc[4], bi1.x), 0.f);
        o[5] = (bf16)fmaxf(fmaf(dv, acc[5], bi1.y), 0.f);
        o[6] = (bf16)fmaxf(fmaf(dv, acc[6], bi1.z), 0.f);
        o[7] = (bf16)fmaxf(fmaf(dv, acc[7], bi1.w), 0.f);
        *(bf16x8*)(&tile[grp][c * 8]) = o;
    }
    __syncthreads();

    // GEMM: A = tile (16x128), B = WT (128x128, [n][k]); wave w does nt=2w,2w+1
    int wave = t >> 6, lane = t & 63;
    int m16 = lane & 15, quad = lane >> 4;
    bf16x8 a[4];
#pragma unroll
    for (int kt = 0; kt < 4; ++kt)
        a[kt] = *(const bf16x8*)(&tile[m16][quad * 8 + kt * 32]);

    int base = blockIdx.x * 16;
    float sc[4];
#pragma unroll
    for (int r = 0; r < 4; ++r) {
        int rr = base + quad * 4 + r;
        sc[r] = (rr < n) ? dinv[rr] : 0.f;
    }

#pragma unroll
    for (int nt2 = 0; nt2 < 2; ++nt2) {
        int nt = wave * 2 + nt2;
        f32x4 accq = {0.f, 0.f, 0.f, 0.f};
        const bf16* brow = WT + (nt * 16 + m16) * D + quad * 8;
#pragma unroll
        for (int kt = 0; kt < 4; ++kt) {
            bf16x8 b = *(const bf16x8*)(brow + kt * 32);
            accq = __builtin_amdgcn_mfma_f32_16x16x32_bf16(a[kt], b, accq, 0, 0, 0);
        }
#pragma unroll
        for (int r = 0; r < 4; ++r)
            C[(size_t)(base + quad * 4 + r) * D + nt * 16 + m16] = (bf16)(sc[r] * accq[r]);
    }
}

// Last layer aggregation fused with mean-pool accumulation (batch-sorted nodes;
// per-block segmented sums flushed with one f32 atomicAdd per segment per dim).
__global__ __launch_bounds__(256) void spmm2_pool_kernel(const bf16* __restrict__ h,
                                                         const int* __restrict__ rowptr,
                                                         const int* __restrict__ csrc,
                                                         const float* __restrict__ dinv,
                                                         const float* __restrict__ bias,
                                                         const int* __restrict__ batch,
                                                         float* __restrict__ gsum, int n) {
    __shared__ float tile[16][D];
    __shared__ int gid[16];
    int t = threadIdx.x;
    int grp = t >> 4;
    int c   = t & 15;
    int v   = blockIdx.x * 16 + grp;
    float dv, acc[8];
    agg_node(h, v, n, c, rowptr, csrc, dinv, dv, acc);
    float4 bi0 = *(const float4*)(bias + c * 8);
    float4 bi1 = *(const float4*)(bias + c * 8 + 4);
    float r0 = fmaxf(fmaf(dv, acc[0], bi0.x), 0.f);
    float r1 = fmaxf(fmaf(dv, acc[1], bi0.y), 0.f);
    float r2 = fmaxf(fmaf(dv, acc[2], bi0.z), 0.f);
    float r3 = fmaxf(fmaf(dv, acc[3], bi0.w), 0.f);
    float r4 = fmaxf(fmaf(dv, acc[4], bi1.x), 0.f);
    float r5 = fmaxf(fmaf(dv, acc[5], bi1.y), 0.f);
    float r6 = fmaxf(fmaf(dv, acc[6], bi1.z), 0.f);
    float r7 = fmaxf(fmaf(dv, acc[7], bi1.w), 0.f);
    if (v >= n) { r0 = r1 = r2 = r3 = r4 = r5 = r6 = r7 = 0.f; }  // relu(bias)!=0
    tile[grp][c * 8 + 0] = r0; tile[grp][c * 8 + 1] = r1;
    tile[grp][c * 8 + 2] = r2; tile[grp][c * 8 + 3] = r3;
    tile[grp][c * 8 + 4] = r4; tile[grp][c * 8 + 5] = r5;
    tile[grp][c * 8 + 6] = r6; tile[grp][c * 8 + 7] = r7;
    if (c == 0) gid[grp] = (v < n) ? batch[v] : -1;
    __syncthreads();
    if (t < D) {
        int curg = gid[0];
        float sum = 0.f;
        if (curg >= 0) {
#pragma unroll 1
            for (int k = 0; k < 16; ++k) {
                int gg = gid[k];
                if (gg < 0) break;               // padding only trails
                if (gg != curg) {
                    atomicAdd(&gsum[(size_t)curg * D + t], sum);
                    curg = gg; sum = 0.f;
                }
                sum += tile[k][t];
            }
            atomicAdd(&gsum[(size_t)curg * D + t], sum);
        }
    }
}

// FC head over pooled sums: pr = gsum/count, 2-layer MLP. One block/graph.
__global__ __launch_bounds__(256) void fc_head_kernel(const float* __restrict__ gsum,
                                                      const int* __restrict__ starts,
                                                      const float* __restrict__ Wfc,
                                                      const float* __restrict__ bfc,
                                                      const float* __restrict__ Wfc2,
                                                      const float* __restrict__ bfc2,
                                                      float* __restrict__ out) {
    __shared__ float pr[D];
    __shared__ float hid[D_FF];
    __shared__ float red[N_CLASSES][9];
    int g = blockIdx.x, t = threadIdx.x;
    if (t < D) {
        float ccount = fmaxf((float)(starts[g + 1] - starts[g]), 1.0f);
        pr[t] = gsum[(size_t)g * D + t] / ccount;
    }
    __syncthreads();
    float a0 = 0.f, a1 = 0.f, a2 = 0.f, a3 = 0.f;
    for (int k = 0; k < D; k += 4) {
        a0 = fmaf(pr[k],     Wfc[k * D_FF + t],       a0);
        a1 = fmaf(pr[k + 1], Wfc[(k + 1) * D_FF + t], a1);
        a2 = fmaf(pr[k + 2], Wfc[(k + 2) * D_FF + t], a2);
        a3 = fmaf(pr[k + 3], Wfc[(k + 3) * D_FF + t], a3);
    }
    hid[t] = fmaxf((a0 + a1) + (a2 + a3) + bfc[t], 0.f);
    __syncthreads();
    if (t < N_CLASSES * 8) {
        int cls = t >> 3, kk = t & 7;
        float o = 0.f;
        for (int k = kk; k < D_FF; k += 8)
            o = fmaf(hid[k], Wfc2[k * N_CLASSES + cls], o);
        red[cls][kk] = o;
    }
    __syncthreads();
    if (t < N_CLASSES) {
        float o = bfc2[t];
#pragma unroll
        for (int k = 0; k < 8; ++k) o += red[t][k];
        out[g * N_CLASSES + t] = o;
    }
}

// ---------------- launch ----------------

extern "C" void kernel_launch(void* const* d_in, const int* in_sizes, int n_in,
                              void* d_out, int out_size, void* d_ws, size_t ws_size,
                              hipStream_t stream) {
    const float* x     = (const float*)d_in[0];
    const int*   eidx  = (const int*)d_in[1];
    const int*   batch = (const int*)d_in[2];
    const float* W[3]  = { (const float*)d_in[3], (const float*)d_in[5], (const float*)d_in[7] };
    const float* b[3]  = { (const float*)d_in[4], (const float*)d_in[6], (const float*)d_in[8] };
    const float* Wfc   = (const float*)d_in[9];
    const float* bfc   = (const float*)d_in[10];
    const float* Wfc2  = (const float*)d_in[11];
    const float* bfc2  = (const float*)d_in[12];
    float* out = (float*)d_out;

    const int E = in_sizes[1] / 2;           // 3,200,000
    const int N = in_sizes[0] / D;           // 100,000
    const int* esrc = eidx;
    const int* edst = eidx + E;

    uint8_t* base = (uint8_t*)d_ws;
    size_t off = 0;
    auto alloc = [&](size_t bytes) -> void* {
        void* p = base + off;
        off = (off + bytes + 255) & ~(size_t)255;
        return p;
    };
    bf16*  hA     = (bf16*) alloc((size_t)N_PAD * D * 2);   // bf16 gather table
    bf16*  hB     = (bf16*) alloc((size_t)N_PAD * D * 2);
    bf16*  WT3    = (bf16*) alloc((size_t)3 * D * D * 2);
    int*   csrc   = (int*)  alloc((size_t)E * 4);
    int*   ebuf   = (int*)  alloc((size_t)E * 4);
    int*   gcount = (int*)  alloc((size_t)NBUCK * NB1 * 4);
    int*   rowptr = (int*)  alloc((size_t)(N + 1) * 4);
    float* dinv   = (float*)alloc((size_t)N * 4);
    int*   starts = (int*)  alloc((size_t)(N_GRAPHS + 1) * 4);
    float* gsum   = (float*)alloc((size_t)N_GRAPHS * D * 4);
    (void)ws_size; (void)n_in; (void)out_size;

    const int GB  = N_PAD / 64;                         // 1563
    const int SGB = (N + 15) / 16;                      // 6250 agg blocks

    // CSR build + misc (3 launches, self-scanning)
    p1misc_kernel<<<NB1 + 65, 1024, 0, stream>>>(edst, gcount, E, batch, starts, N,
                                                 W[0], W[1], W[2], WT3, gsum);
    p3_scatter<<<NB1, 1024, 0, stream>>>(gcount, esrc, edst, ebuf, E);
    p45_fill<<<NBUCK, 1024, 0, stream>>>(gcount, ebuf, dinv, rowptr, csrc, E, N);

    // layer 1 input-side GEMM: g1 = dinv * (x @ W1)
    gemm_f32_kernel<<<GB, 256, 0, stream>>>(x, WT3, hA, dinv, N);
    // fused layer1-agg + W2: g2 = dinv * (relu(...b1) @ W2)
    spmm_gemm_kernel<<<SGB, 256, 0, stream>>>(hA, rowptr, csrc, dinv, b[0],
                                              WT3 + (size_t)1 * D * D, hB, N);
    // fused layer2-agg + W3: g3 = dinv * (relu(...b2) @ W3)
    spmm_gemm_kernel<<<SGB, 256, 0, stream>>>(hB, rowptr, csrc, dinv, b[1],
                                              WT3 + (size_t)2 * D * D, hA, N);
    // layer 3 aggregation fused with mean-pool accumulation
    spmm2_pool_kernel<<<SGB, 256, 0, stream>>>(hA, rowptr, csrc, dinv, b[2],
                                               batch, gsum, N);

    // FC head on pooled sums
    fc_head_kernel<<<N_GRAPHS, 256, 0, stream>>>(gsum, starts, Wfc, bfc, Wfc2, bfc2, out);
}

// Round 12
// 568.681 us; speedup vs baseline: 1.0204x; 1.0204x over previous
//
#include <hip/hip_runtime.h>
#include <hip/hip_bf16.h>

typedef __bf16 bf16;
typedef __attribute__((ext_vector_type(8))) __bf16 bf16x8;
typedef __attribute__((ext_vector_type(4))) float f32x4;

constexpr int N_NODES   = 100000;
constexpr int N_PAD     = 100032;   // multiple of 64
constexpr int D         = 128;
constexpr int D_FF      = 256;
constexpr int N_CLASSES = 26;
constexpr int N_GRAPHS  = 512;
constexpr int NB1       = 256;                       // partition blocks (CSR build)
constexpr int NBUCK     = (N_NODES + 511) / 512;     // 196 dst-buckets of 512 nodes

__device__ inline float2 bf2f(unsigned u) {
    float lo = __uint_as_float(u << 16);
    float hi = __uint_as_float(u & 0xffff0000u);
    return make_float2(lo, hi);
}

// ---------------- CSR build: atomic-free bucket counting sort ----------------
// R23: 3 launches. p3/p45 recompute their own prefix slices from the 200KB
// L2-resident gcount.

// p1 histogram (blocks 0..255) + misc work (blocks 256..320) in ONE launch.
__global__ __launch_bounds__(1024) void p1misc_kernel(const int* __restrict__ edst,
                                                      int* __restrict__ gcount, int e,
                                                      const int* __restrict__ batch,
                                                      int* __restrict__ starts, int n,
                                                      const float* __restrict__ W0,
                                                      const float* __restrict__ W1,
                                                      const float* __restrict__ W2,
                                                      bf16* __restrict__ WT3,
                                                      float* __restrict__ gsum) {
    int t = threadIdx.x;
    if (blockIdx.x < NB1) {
        __shared__ int cnt[NBUCK];
        for (int q = t; q < NBUCK; q += 1024) cnt[q] = 0;
        __syncthreads();
        int chunk = (e + NB1 - 1) / NB1;
        int lo = blockIdx.x * chunk;
        int hi = min(e, lo + chunk);
        for (int i = lo + t; i < hi; i += 1024)
            atomicAdd(&cnt[edst[i] >> 9], 1);
        __syncthreads();
        for (int q = t; q < NBUCK; q += 1024)
            gcount[q * NB1 + blockIdx.x] = cnt[q];
    } else {
        int mb = blockIdx.x - NB1;                 // 0..64
        if (mb == 0) {
            if (t <= N_GRAPHS) {                   // starts[g] = lower_bound(batch,g)
                int lo = 0, hi = n;
                while (lo < hi) {
                    int mid = (lo + hi) >> 1;
                    if (batch[mid] < t) lo = mid + 1; else hi = mid;
                }
                starts[t] = lo;
            }
        } else if (mb <= 48) {
            int idx = (mb - 1) * 1024 + t;         // 0..49151 == 3*128*128
            int l = idx >> 14;
            int rem = idx & 16383;
            int nn = rem >> 7;
            int kk = rem & 127;
            const float* W = (l == 0) ? W0 : (l == 1) ? W1 : W2;
            WT3[idx] = (bf16)W[kk * D + nn];       // WT3[l][n][k] = W[k][n]
        } else {
            int idx = (mb - 49) * 1024 + t;        // 16384 float4 = 512*128 f32
            f32x4 z = {0.f, 0.f, 0.f, 0.f};
            *((f32x4*)gsum + idx) = z;
        }
    }
}

// R23 self-scanning scatter: block b derives its per-bucket cursors directly
// from gcount: cur[t] = bucketbase[t] + sum_{c<b} gcount[t][c].
__global__ __launch_bounds__(1024) void p3_scatter(const int* __restrict__ gcount,
                                                   const int* __restrict__ esrc,
                                                   const int* __restrict__ edst,
                                                   int* __restrict__ ebuf, int e) {
    __shared__ int cur[NBUCK];
    __shared__ int tot[NBUCK];
    int t = threadIdx.x;
    int b = blockIdx.x;
    if (t < NBUCK) {
        int sum = 0, part = 0;
        const int* row = gcount + t * NB1;
        for (int c = 0; c < NB1; ++c) {
            int v = row[c];
            sum += v;
            part += (c < b) ? v : 0;
        }
        tot[t] = sum;
        cur[t] = part;
    }
    __syncthreads();
    for (int off = 1; off < NBUCK; off <<= 1) {   // inclusive scan of tot
        int v = (t >= off && t < NBUCK) ? tot[t - off] : 0;
        __syncthreads();
        if (t < NBUCK) tot[t] += v;
        __syncthreads();
    }
    if (t < NBUCK) cur[t] += (t > 0) ? tot[t - 1] : 0;   // + exclusive bucketbase
    __syncthreads();
    int chunk = (e + NB1 - 1) / NB1;
    int lo = b * chunk;
    int hi = min(e, lo + chunk);
    for (int i = lo + t; i < hi; i += 1024) {
        int d = edst[i], s = esrc[i];
        int pos = atomicAdd(&cur[d >> 9], 1);   // LDS atomic
        ebuf[pos] = (s << 9) | (d & 511);
    }
}

// R23 self-scanning P45: block b reduces its own lo/hi from gcount, then runs
// the fused per-bucket degree count + LDS scan + CSR fill.
__global__ __launch_bounds__(1024) void p45_fill(const int* __restrict__ gcount,
                                                 const int* __restrict__ ebuf,
                                                 float* __restrict__ dinv,
                                                 int* __restrict__ rowptr,
                                                 int* __restrict__ csrc, int e, int n) {
    __shared__ int red[1024];
    __shared__ int cnt[512];
    __shared__ int ps[512];
    __shared__ int cur[512];
    int b = blockIdx.x, t = threadIdx.x;
    // --- prefix slices from gcount ---
    int s1 = 0;
    for (int idx = t; idx < b * NB1; idx += 1024) s1 += gcount[idx];
    red[t] = s1; __syncthreads();
#pragma unroll
    for (int off = 512; off > 0; off >>= 1) {
        if (t < off) red[t] += red[t + off];
        __syncthreads();
    }
    int lo = red[0];
    __syncthreads();
    red[t] = (t < NB1) ? gcount[b * NB1 + t] : 0; __syncthreads();
#pragma unroll
    for (int off = 512; off > 0; off >>= 1) {
        if (t < off) red[t] += red[t + off];
        __syncthreads();
    }
    int hi = lo + red[0];
    __syncthreads();
    // --- original p45 body ---
    if (t < 512) cnt[t] = 0;
    __syncthreads();
    for (int i = lo + t; i < hi; i += 1024)
        atomicAdd(&cnt[ebuf[i] & 511], 1);      // LDS atomic
    __syncthreads();
    int a = (t < 512) ? cnt[t] : 0;
    if (t < 512) ps[t] = a;
    __syncthreads();
    for (int off = 1; off < 512; off <<= 1) {
        int v = (t >= off && t < 512) ? ps[t - off] : 0;
        __syncthreads();
        if (t < 512) ps[t] += v;
        __syncthreads();
    }
    if (t < 512) {
        int g0 = lo + ps[t] - a;             // global CSR slot of node b*512+t
        int node = b * 512 + t;
        cur[t] = g0;
        if (node < n) {
            rowptr[node] = g0;
            dinv[node] = 1.0f / sqrtf((float)(a + 1));   // +1 self-loop
        }
    }
    if (b == 0 && t == 0) rowptr[n] = e;
    __syncthreads();
    for (int i = lo + t; i < hi; i += 1024) {
        int pe = ebuf[i];
        int pos = atomicAdd(&cur[pe & 511], 1);  // LDS atomic
        csrc[pos] = pe >> 9;
    }
}

// ---------------- dense compute ----------------

// Layer-1: C[row][:] = bf16( dinv[row] * ((f32)A @ W)[row][:] ) — gather table g1.
__global__ __launch_bounds__(256) void gemm_f32_kernel(const float* __restrict__ A,
                                                       const bf16* __restrict__ WT,
                                                       bf16* __restrict__ C,
                                                       const float* __restrict__ dinv, int n) {
    int wave = threadIdx.x >> 6;
    int lane = threadIdx.x & 63;
    int m16  = lane & 15;
    int quad = lane >> 4;
    int row0 = blockIdx.x * 64 + wave * 16;
    int arowi = row0 + m16;

    bf16x8 a[4];
    const float* arow = A + (size_t)arowi * D + quad * 8;
#pragma unroll
    for (int kt = 0; kt < 4; ++kt) {
        float4 f0 = make_float4(0.f, 0.f, 0.f, 0.f);
        float4 f1 = make_float4(0.f, 0.f, 0.f, 0.f);
        if (arowi < n) {
            f0 = *(const float4*)(arow + kt * 32);
            f1 = *(const float4*)(arow + kt * 32 + 4);
        }
        bf16x8 v = { (bf16)f0.x, (bf16)f0.y, (bf16)f0.z, (bf16)f0.w,
                     (bf16)f1.x, (bf16)f1.y, (bf16)f1.z, (bf16)f1.w };
        a[kt] = v;
    }

    float sc[4];
#pragma unroll
    for (int r = 0; r < 4; ++r) {
        int rr = row0 + quad * 4 + r;
        sc[r] = (rr < n) ? dinv[rr] : 0.f;
    }

#pragma unroll
    for (int nt = 0; nt < 8; ++nt) {
        f32x4 acc = {0.f, 0.f, 0.f, 0.f};
        const bf16* brow = WT + (nt * 16 + m16) * D + quad * 8;
#pragma unroll
        for (int kt = 0; kt < 4; ++kt) {
            bf16x8 b = *(const bf16x8*)(brow + kt * 32);
            acc = __builtin_amdgcn_mfma_f32_16x16x32_bf16(a[kt], b, acc, 0, 0, 0);
        }
#pragma unroll
        for (int r = 0; r < 4; ++r)
            C[(row0 + quad * 4 + r) * D + nt * 16 + m16] = (bf16)(sc[r] * acc[r]);
    }
}

// ---------------- aggregation core (16 lanes own one node) ----------------
// acc = g[v] + sum_e g[src]   (table g pre-scaled by dinv[src])
// R25: depth is per-call-site. DEEP8 in spmm_gemm (R24: -3.2us/dispatch);
// 4-deep in spmm2_pool (R24 showed 8-deep + f32 tile there regresses net).
__device__ inline void acc_u4(float acc[8], uint4 u) {
    float2 f0 = bf2f(u.x), f1 = bf2f(u.y), f2 = bf2f(u.z), f3 = bf2f(u.w);
    acc[0] += f0.x; acc[1] += f0.y; acc[2] += f1.x; acc[3] += f1.y;
    acc[4] += f2.x; acc[5] += f2.y; acc[6] += f3.x; acc[7] += f3.y;
}

template <bool DEEP8>
__device__ inline void agg_node(const bf16* __restrict__ h, int v, int n, int c,
                                const int* __restrict__ rowptr,
                                const int* __restrict__ csrc,
                                const float* __restrict__ dinv,
                                float& dv, float acc[8]) {
    int s = 0, e = 0;
    dv = 0.f;
    if (v < n) { s = rowptr[v]; e = rowptr[v + 1]; dv = dinv[v]; }
#pragma unroll
    for (int d = 0; d < 8; ++d) acc[d] = 0.f;
    if (v < n) {
        uint4 u = *(const uint4*)(h + (size_t)v * D + c * 8);
        acc_u4(acc, u);
    }
    int j = s;
    if (DEEP8) {
        for (; j + 7 < e; j += 8) {
            int s0 = csrc[j],     s1 = csrc[j + 1], s2 = csrc[j + 2], s3 = csrc[j + 3];
            int s4 = csrc[j + 4], s5 = csrc[j + 5], s6 = csrc[j + 6], s7 = csrc[j + 7];
            uint4 u0 = *(const uint4*)(h + (size_t)s0 * D + c * 8);
            uint4 u1 = *(const uint4*)(h + (size_t)s1 * D + c * 8);
            uint4 u2 = *(const uint4*)(h + (size_t)s2 * D + c * 8);
            uint4 u3 = *(const uint4*)(h + (size_t)s3 * D + c * 8);
            uint4 u4 = *(const uint4*)(h + (size_t)s4 * D + c * 8);
            uint4 u5 = *(const uint4*)(h + (size_t)s5 * D + c * 8);
            uint4 u6 = *(const uint4*)(h + (size_t)s6 * D + c * 8);
            uint4 u7 = *(const uint4*)(h + (size_t)s7 * D + c * 8);
            acc_u4(acc, u0); acc_u4(acc, u1); acc_u4(acc, u2); acc_u4(acc, u3);
            acc_u4(acc, u4); acc_u4(acc, u5); acc_u4(acc, u6); acc_u4(acc, u7);
        }
    }
    for (; j + 3 < e; j += 4) {
        int s0 = csrc[j], s1 = csrc[j + 1], s2 = csrc[j + 2], s3 = csrc[j + 3];
        uint4 u0 = *(const uint4*)(h + (size_t)s0 * D + c * 8);
        uint4 u1 = *(const uint4*)(h + (size_t)s1 * D + c * 8);
        uint4 u2 = *(const uint4*)(h + (size_t)s2 * D + c * 8);
        uint4 u3 = *(const uint4*)(h + (size_t)s3 * D + c * 8);
        acc_u4(acc, u0); acc_u4(acc, u1); acc_u4(acc, u2); acc_u4(acc, u3);
    }
    for (; j < e; ++j) {
        int s0 = csrc[j];
        uint4 u0 = *(const uint4*)(h + (size_t)s0 * D + c * 8);
        acc_u4(acc, u0);
    }
}

// Fused: aggregate layer l (16 nodes/block), relu-tile in LDS, then the
// block's 4 waves multiply by W_{l+1} (MFMA) and write the NEXT gather table
// g' = dinv * (h_l @ W_{l+1}).
__global__ __launch_bounds__(256) void spmm_gemm_kernel(const bf16* __restrict__ h,
                                                        const int* __restrict__ rowptr,
                                                        const int* __restrict__ csrc,
                                                        const float* __restrict__ dinv,
                                                        const float* __restrict__ bias,
                                                        const bf16* __restrict__ WT,
                                                        bf16* __restrict__ C, int n) {
    __shared__ bf16 tile[16][136];          // +8 bf16 row pad (bank spread)
    int t = threadIdx.x;
    int grp = t >> 4;                        // node within block
    int c   = t & 15;                        // dim chunk
    int v   = blockIdx.x * 16 + grp;
    float dv, acc[8];
    agg_node<true>(h, v, n, c, rowptr, csrc, dinv, dv, acc);
    {
        float4 bi0 = *(const float4*)(bias + c * 8);
        float4 bi1 = *(const float4*)(bias + c * 8 + 4);
        bf16x8 o;
        o[0] = (bf16)fmaxf(fmaf(dv, acc[0], bi0.x), 0.f);
        o[1] = (bf16)fmaxf(fmaf(dv, acc[1], bi0.y), 0.f);
        o[2] = (bf16)fmaxf(fmaf(dv, acc[2], bi0.z), 0.f);
        o[3] = (bf16)fmaxf(fmaf(dv, acc[3], bi0.w), 0.f);
        o[4] = (bf16)fmaxf(fmaf(dv, acc[4], bi1.x), 0.f);
        o[5] = (bf16)fmaxf(fmaf(dv, acc[5], bi1.y), 0.f);
        o[6] = (bf16)fmaxf(fmaf(dv, acc[6], bi1.z), 0.f);
        o[7] = (bf16)fmaxf(fmaf(dv, acc[7], bi1.w), 0.f);
        *(bf16x8*)(&tile[grp][c * 8]) = o;
    }
    __syncthreads();

    // GEMM: A = tile (16x128), B = WT (128x128, [n][k]); wave w does nt=2w,2w+1
    int wave = t >> 6, lane = t & 63;
    int m16 = lane & 15, quad = lane >> 4;
    bf16x8 a[4];
#pragma unroll
    for (int kt = 0; kt < 4; ++kt)
        a[kt] = *(const bf16x8*)(&tile[m16][quad * 8 + kt * 32]);

    int base = blockIdx.x * 16;
    float sc[4];
#pragma unroll
    for (int r = 0; r < 4; ++r) {
        int rr = base + quad * 4 + r;
        sc[r] = (rr < n) ? dinv[rr] : 0.f;
    }

#pragma unroll
    for (int nt2 = 0; nt2 < 2; ++nt2) {
        int nt = wave * 2 + nt2;
        f32x4 accq = {0.f, 0.f, 0.f, 0.f};
        const bf16* brow = WT + (nt * 16 + m16) * D + quad * 8;
#pragma unroll
        for (int kt = 0; kt < 4; ++kt) {
            bf16x8 b = *(const bf16x8*)(brow + kt * 32);
            accq = __builtin_amdgcn_mfma_f32_16x16x32_bf16(a[kt], b, accq, 0, 0, 0);
        }
#pragma unroll
        for (int r = 0; r < 4; ++r)
            C[(size_t)(base + quad * 4 + r) * D + nt * 16 + m16] = (bf16)(sc[r] * accq[r]);
    }
}

// Last layer aggregation fused with mean-pool accumulation (batch-sorted nodes;
// per-block segmented sums flushed with one f32 atomicAdd per segment per dim).
__global__ __launch_bounds__(256) void spmm2_pool_kernel(const bf16* __restrict__ h,
                                                         const int* __restrict__ rowptr,
                                                         const int* __restrict__ csrc,
                                                         const float* __restrict__ dinv,
                                                         const float* __restrict__ bias,
                                                         const int* __restrict__ batch,
                                                         float* __restrict__ gsum, int n) {
    __shared__ float tile[16][D];
    __shared__ int gid[16];
    int t = threadIdx.x;
    int grp = t >> 4;
    int c   = t & 15;
    int v   = blockIdx.x * 16 + grp;
    float dv, acc[8];
    agg_node<false>(h, v, n, c, rowptr, csrc, dinv, dv, acc);
    float4 bi0 = *(const float4*)(bias + c * 8);
    float4 bi1 = *(const float4*)(bias + c * 8 + 4);
    float r0 = fmaxf(fmaf(dv, acc[0], bi0.x), 0.f);
    float r1 = fmaxf(fmaf(dv, acc[1], bi0.y), 0.f);
    float r2 = fmaxf(fmaf(dv, acc[2], bi0.z), 0.f);
    float r3 = fmaxf(fmaf(dv, acc[3], bi0.w), 0.f);
    float r4 = fmaxf(fmaf(dv, acc[4], bi1.x), 0.f);
    float r5 = fmaxf(fmaf(dv, acc[5], bi1.y), 0.f);
    float r6 = fmaxf(fmaf(dv, acc[6], bi1.z), 0.f);
    float r7 = fmaxf(fmaf(dv, acc[7], bi1.w), 0.f);
    if (v >= n) { r0 = r1 = r2 = r3 = r4 = r5 = r6 = r7 = 0.f; }  // relu(bias)!=0
    tile[grp][c * 8 + 0] = r0; tile[grp][c * 8 + 1] = r1;
    tile[grp][c * 8 + 2] = r2; tile[grp][c * 8 + 3] = r3;
    tile[grp][c * 8 + 4] = r4; tile[grp][c * 8 + 5] = r5;
    tile[grp][c * 8 + 6] = r6; tile[grp][c * 8 + 7] = r7;
    if (c == 0) gid[grp] = (v < n) ? batch[v] : -1;
    __syncthreads();
    if (t < D) {
        int curg = gid[0];
        float sum = 0.f;
        if (curg >= 0) {
#pragma unroll 1
            for (int k = 0; k < 16; ++k) {
                int gg = gid[k];
                if (gg < 0) break;               // padding only trails
                if (gg != curg) {
                    atomicAdd(&gsum[(size_t)curg * D + t], sum);
                    curg = gg; sum = 0.f;
                }
                sum += tile[k][t];
            }
            atomicAdd(&gsum[(size_t)curg * D + t], sum);
        }
    }
}

// FC head over pooled sums: pr = gsum/count, 2-layer MLP. One block/graph.
__global__ __launch_bounds__(256) void fc_head_kernel(const float* __restrict__ gsum,
                                                      const int* __restrict__ starts,
                                                      const float* __restrict__ Wfc,
                                                      const float* __restrict__ bfc,
                                                      const float* __restrict__ Wfc2,
                                                      const float* __restrict__ bfc2,
                                                      float* __restrict__ out) {
    __shared__ float pr[D];
    __shared__ float hid[D_FF];
    __shared__ float red[N_CLASSES][9];
    int g = blockIdx.x, t = threadIdx.x;
    if (t < D) {
        float ccount = fmaxf((float)(starts[g + 1] - starts[g]), 1.0f);
        pr[t] = gsum[(size_t)g * D + t] / ccount;
    }
    __syncthreads();
    float a0 = 0.f, a1 = 0.f, a2 = 0.f, a3 = 0.f;
    for (int k = 0; k < D; k += 4) {
        a0 = fmaf(pr[k],     Wfc[k * D_FF + t],       a0);
        a1 = fmaf(pr[k + 1], Wfc[(k + 1) * D_FF + t], a1);
        a2 = fmaf(pr[k + 2], Wfc[(k + 2) * D_FF + t], a2);
        a3 = fmaf(pr[k + 3], Wfc[(k + 3) * D_FF + t], a3);
    }
    hid[t] = fmaxf((a0 + a1) + (a2 + a3) + bfc[t], 0.f);
    __syncthreads();
    if (t < N_CLASSES * 8) {
        int cls = t >> 3, kk = t & 7;
        float o = 0.f;
        for (int k = kk; k < D_FF; k += 8)
            o = fmaf(hid[k], Wfc2[k * N_CLASSES + cls], o);
        red[cls][kk] = o;
    }
    __syncthreads();
    if (t < N_CLASSES) {
        float o = bfc2[t];
#pragma unroll
        for (int k = 0; k < 8; ++k) o += red[t][k];
        out[g * N_CLASSES + t] = o;
    }
}

// ---------------- launch ----------------

extern "C" void kernel_launch(void* const* d_in, const int* in_sizes, int n_in,
                              void* d_out, int out_size, void* d_ws, size_t ws_size,
                              hipStream_t stream) {
    const float* x     = (const float*)d_in[0];
    const int*   eidx  = (const int*)d_in[1];
    const int*   batch = (const int*)d_in[2];
    const float* W[3]  = { (const float*)d_in[3], (const float*)d_in[5], (const float*)d_in[7] };
    const float* b[3]  = { (const float*)d_in[4], (const float*)d_in[6], (const float*)d_in[8] };
    const float* Wfc   = (const float*)d_in[9];
    const float* bfc   = (const float*)d_in[10];
    const float* Wfc2  = (const float*)d_in[11];
    const float* bfc2  = (const float*)d_in[12];
    float* out = (float*)d_out;

    const int E = in_sizes[1] / 2;           // 3,200,000
    const int N = in_sizes[0] / D;           // 100,000
    const int* esrc = eidx;
    const int* edst = eidx + E;

    uint8_t* base = (uint8_t*)d_ws;
    size_t off = 0;
    auto alloc = [&](size_t bytes) -> void* {
        void* p = base + off;
        off = (off + bytes + 255) & ~(size_t)255;
        return p;
    };
    bf16*  hA     = (bf16*) alloc((size_t)N_PAD * D * 2);   // bf16 gather table
    bf16*  hB     = (bf16*) alloc((size_t)N_PAD * D * 2);
    bf16*  WT3    = (bf16*) alloc((size_t)3 * D * D * 2);
    int*   csrc   = (int*)  alloc((size_t)E * 4);
    int*   ebuf   = (int*)  alloc((size_t)E * 4);
    int*   gcount = (int*)  alloc((size_t)NBUCK * NB1 * 4);
    int*   rowptr = (int*)  alloc((size_t)(N + 1) * 4);
    float* dinv   = (float*)alloc((size_t)N * 4);
    int*   starts = (int*)  alloc((size_t)(N_GRAPHS + 1) * 4);
    float* gsum   = (float*)alloc((size_t)N_GRAPHS * D * 4);
    (void)ws_size; (void)n_in; (void)out_size;

    const int GB  = N_PAD / 64;                         // 1563
    const int SGB = (N + 15) / 16;                      // 6250 agg blocks

    // CSR build + misc (3 launches, self-scanning)
    p1misc_kernel<<<NB1 + 65, 1024, 0, stream>>>(edst, gcount, E, batch, starts, N,
                                                 W[0], W[1], W[2], WT3, gsum);
    p3_scatter<<<NB1, 1024, 0, stream>>>(gcount, esrc, edst, ebuf, E);
    p45_fill<<<NBUCK, 1024, 0, stream>>>(gcount, ebuf, dinv, rowptr, csrc, E, N);

    // layer 1 input-side GEMM: g1 = dinv * (x @ W1)
    gemm_f32_kernel<<<GB, 256, 0, stream>>>(x, WT3, hA, dinv, N);
    // fused layer1-agg + W2: g2 = dinv * (relu(...b1) @ W2)  [8-deep gather]
    spmm_gemm_kernel<<<SGB, 256, 0, stream>>>(hA, rowptr, csrc, dinv, b[0],
                                              WT3 + (size_t)1 * D * D, hB, N);
    // fused layer2-agg + W3: g3 = dinv * (relu(...b2) @ W3)  [8-deep gather]
    spmm_gemm_kernel<<<SGB, 256, 0, stream>>>(hB, rowptr, csrc, dinv, b[1],
                                              WT3 + (size_t)2 * D * D, hA, N);
    // layer 3 aggregation fused with mean-pool accumulation   [4-deep gather]
    spmm2_pool_kernel<<<SGB, 256, 0, stream>>>(hA, rowptr, csrc, dinv, b[2],
                                               batch, gsum, N);

    // FC head on pooled sums
    fc_head_kernel<<<N_GRAPHS, 256, 0, stream>>>(gsum, starts, Wfc, bfc, Wfc2, bfc2, out);
}